// Round 8
// baseline (128.577 us; speedup 1.0000x reference)
//
#include <hip/hip_runtime.h>
#include <math.h>

// Output layout: [N][X=32][Y=32][Z=32][3] float32, N=1024.
// val[n,x,y,z,d] = -0.5*t^2 - 0.5*log(2*pi),
//   t = idx_d*s - b_d,  s = pitch*inv,  b_d = (15.5*pitch + p[n,d])*inv,
//   inv = 1/(conf[n]*pitch)   (ALPHA = 1)
//
// R7 DIAGNOSTIC: R0's exact kernel, but the store phase runs `passes`=4
// times (idempotent — same values to same addresses; asm memory clobber
// stops store-collapsing). Purpose: push this dispatch to ~310us so it
// appears in the top-5 counter table, giving our first direct read of
// WRITE_SIZE / FETCH_SIZE / VALUBusy / OccupancyPercent for this kernel.
// dur_us this round is a throwaway.

#define HALF_LOG_2PI 0.91893853320467274178f

typedef float f32x4 __attribute__((ext_vector_type(4)));

__global__ __launch_bounds__(256) void pbt_kernel(
    const float* __restrict__ points,
    const float* __restrict__ confs,
    const float* __restrict__ pitch_p,
    float* __restrict__ out,
    int passes)
{
    const unsigned block = blockIdx.x;
    const unsigned n = block >> 5;
    const unsigned x = block & 31u;

    const float pitch = pitch_p[0];
    const float conf  = confs[n];
    const float inv   = 1.0f / (conf * pitch);
    const float s     = pitch * inv;
    const float off   = 15.5f * pitch;
    const float bx = (off + points[n * 3 + 0]) * inv;
    const float by = (off + points[n * 3 + 1]) * inv;
    const float bz = (off + points[n * 3 + 2]) * inv;

    const float tx = (float)x * s - bx;
    const float vx = fmaf(-0.5f * tx, tx, -HALF_LOG_2PI);

    f32x4* o = (f32x4*)(out + (size_t)block * 3072u);
    const unsigned t = threadIdx.x;

    // Values are pass-invariant; compiler hoists compute, loop re-issues
    // only the 3 stores per pass. Memory clobber prevents store collapsing.
    for (int p = 0; p < passes; ++p) {
        #pragma unroll
        for (int k = 0; k < 3; ++k) {
            const unsigned f4 = t + (unsigned)k * 256u;  // float4 idx, 0..767
            const unsigned e0 = f4 * 4u;
            float v[4];
            #pragma unroll
            for (int j = 0; j < 4; ++j) {
                const unsigned e  = e0 + (unsigned)j;
                const unsigned d  = e % 3u;
                const unsigned zi = e / 3u;
                const unsigned y  = zi >> 5;
                const unsigned zz = zi & 31u;
                const float ty = (float)y  * s - by;
                const float tz = (float)zz * s - bz;
                const float vy = fmaf(-0.5f * ty, ty, -HALF_LOG_2PI);
                const float vz = fmaf(-0.5f * tz, tz, -HALF_LOG_2PI);
                v[j] = (d == 0u) ? vx : ((d == 1u) ? vy : vz);
            }
            f32x4 vv = { v[0], v[1], v[2], v[3] };
            o[f4] = vv;
        }
        asm volatile("" ::: "memory");
    }
}

extern "C" void kernel_launch(void* const* d_in, const int* in_sizes, int n_in,
                              void* d_out, int out_size, void* d_ws, size_t ws_size,
                              hipStream_t stream) {
    const float* points = (const float*)d_in[0];  // [N,3]
    const float* confs  = (const float*)d_in[1];  // [N]
    // d_in[2] = coordinates [32,32,32,3] — recomputed from pitch on device
    const float* pitch  = (const float*)d_in[3];  // [1]
    float* out = (float*)d_out;

    const int N = in_sizes[0] / 3;        // 1024
    const int blocks = N * 32;            // one block per (n, x)
    pbt_kernel<<<dim3(blocks), dim3(256), 0, stream>>>(points, confs, pitch, out, 4);
}

// Round 9
// 80.421 us; speedup vs baseline: 1.5988x; 1.5988x over previous
//
#include <hip/hip_runtime.h>
#include <math.h>

// Output layout: [N][X=32][Y=32][Z=32][3] float32, N=1024.
// val[n,x,y,z,d] = -0.5*t^2 - 0.5*log(2*pi),
//   t = idx_d*s - b_d,  s = pitch*inv,  b_d = (15.5*pitch + p[n,d])*inv,
//   inv = 1/(conf[n]*pitch)   (ALPHA = 1)
//
// R8: fill-mimic with amortized setup. 1024 persistent blocks (4/CU),
// grid-stride over the 32768 12KB slabs with stride 1024: instantaneous
// store window = ~12MB, compact, advancing sequentially (fill-like), and
// issue pressure is moderated vs R0's full-occupancy flood. Unlike R6,
// per-slab setup (conf/points load + rcp) amortizes over 12KB not 16B,
// and x = slab&31 is loop-invariant per block.

#define HALF_LOG_2PI 0.91893853320467274178f

typedef float f32x4 __attribute__((ext_vector_type(4)));

__global__ __launch_bounds__(256) void pbt_kernel(
    const float* __restrict__ points,
    const float* __restrict__ confs,
    const float* __restrict__ pitch_p,
    float* __restrict__ out)
{
    const unsigned b = blockIdx.x;          // 0..1023
    const unsigned t = threadIdx.x;
    const unsigned x = b & 31u;             // invariant: slab+1024 keeps x

    const float pitch = pitch_p[0];
    const float off   = 15.5f * pitch;

    #pragma unroll 2
    for (unsigned i = 0; i < 32u; ++i) {
        const unsigned slab = b + i * 1024u;    // < 32768
        const unsigned n    = slab >> 5;

        const float conf = confs[n];
        const float inv  = 1.0f / (conf * pitch);
        const float s    = pitch * inv;
        const float bx = (off + points[n * 3u + 0u]) * inv;
        const float by = (off + points[n * 3u + 1u]) * inv;
        const float bz = (off + points[n * 3u + 2u]) * inv;

        const float tx = (float)x * s - bx;
        const float vx = fmaf(-0.5f * tx, tx, -HALF_LOG_2PI);

        f32x4* o = (f32x4*)(out + (size_t)slab * 3072u) + t;
        #pragma unroll
        for (int k = 0; k < 3; ++k) {
            const unsigned e0 = (t + (unsigned)k * 256u) * 4u;
            float v[4];
            #pragma unroll
            for (int j = 0; j < 4; ++j) {
                const unsigned e  = e0 + (unsigned)j;
                const unsigned d  = e % 3u;
                const unsigned zi = e / 3u;
                const unsigned y  = zi >> 5;
                const unsigned zz = zi & 31u;
                const float ty = (float)y  * s - by;
                const float tz = (float)zz * s - bz;
                const float vy = fmaf(-0.5f * ty, ty, -HALF_LOG_2PI);
                const float vz = fmaf(-0.5f * tz, tz, -HALF_LOG_2PI);
                v[j] = (d == 0u) ? vx : ((d == 1u) ? vy : vz);
            }
            f32x4 vv = { v[0], v[1], v[2], v[3] };
            o[k * 256] = vv;
        }
    }
}

extern "C" void kernel_launch(void* const* d_in, const int* in_sizes, int n_in,
                              void* d_out, int out_size, void* d_ws, size_t ws_size,
                              hipStream_t stream) {
    const float* points = (const float*)d_in[0];  // [N,3]
    const float* confs  = (const float*)d_in[1];  // [N]
    // d_in[2] = coordinates [32,32,32,3] — recomputed from pitch on device
    const float* pitch  = (const float*)d_in[3];  // [1]
    float* out = (float*)d_out;

    (void)in_sizes; (void)n_in; (void)out_size; (void)d_ws; (void)ws_size;
    pbt_kernel<<<dim3(1024), dim3(256), 0, stream>>>(points, confs, pitch, out);
}